// Round 4
// baseline (132.592 us; speedup 1.0000x reference)
//
#include <hip/hip_runtime.h>
#include <hip/hip_cooperative_groups.h>
#include <math.h>

namespace cg = cooperative_groups;

// ECDA loss, fully fused cooperative kernel (4 phases + 3 grid syncs).
// Inputs: clean_feats[2048,256] f32, noisy_feats[2048,256] f32,
//         clean_labels[2048] i32, noisy_labels[2048] i32,
//         noisy_mask[2048] f32, noisy_scores[2048] f32, class_weights[8] f32.
// Output: scalar f32.

static constexpr int NC = 8;
static constexpr int NN = 2048;
static constexpr int DD = 256;

// workspace byte offsets
static constexpr int OFF_CNT_S = 0;        // 8 int
static constexpr int OFF_CNT_T = 64;       // 8 int
static constexpr int OFF_SW    = 128;      // 8 f32
static constexpr int OFF_SQS   = 192;      // 8 f32 (atomic accum)
static constexpr int OFF_SQT   = 256;      // 8 f32 (atomic accum)
static constexpr int OFF_INVBW = 384;      // 8*5 f32
static constexpr int OFF_SCC   = 576;      // 8 f32
static constexpr int OFF_SNN   = 640;      // 8 f32
static constexpr int OFF_SCN   = 704;      // 8 f32
static constexpr int OFF_VS    = 4096;     // 8*256 f32 (atomic accum)
static constexpr int OFF_VT    = 12288;    // 8*256 f32 (atomic accum)
static constexpr int OFF_IDX_S = 32768;    // 8*2048 int
static constexpr int OFF_IDX_T = 98304;    // 8*2048 int
static constexpr int OFF_WT    = 163840;   // 8*2048 f32
static constexpr int OFF_QNS   = 229376;   // 8*2048 f32 norms (clean, bf16-rounded)
static constexpr int OFF_QNT   = 294912;   // 8*2048 f32 norms (noisy, bf16-rounded)
// total ~352 KB

typedef __attribute__((ext_vector_type(8))) short bf16x8;
typedef __attribute__((ext_vector_type(4))) float f32x4;

__device__ inline float wred64(float v) {
  for (int o = 32; o > 0; o >>= 1) v += __shfl_xor(v, o, 64);
  return v;
}
__device__ inline short f2bf(float x) {
  unsigned u = __float_as_uint(x);
  return (short)((u + 0x7fffu + ((u >> 16) & 1u)) >> 16);
}
__device__ inline float rbf(float x) {
  unsigned u = __float_as_uint(x);
  u = (u + 0x7fffu + ((u >> 16) & 1u)) & 0xffff0000u;
  return __uint_as_float(u);
}

__global__ __launch_bounds__(256, 1) void ecda_all(
    const float* __restrict__ cfeat, const float* __restrict__ nfeat,
    const int* __restrict__ clab, const int* __restrict__ nlab,
    const float* __restrict__ nmask, const float* __restrict__ nscore,
    const float* __restrict__ cw, char* __restrict__ ws,
    float* __restrict__ out) {
  cg::grid_group grid = cg::this_grid();
  const int tid = threadIdx.x;
  const int bx = blockIdx.x;
  const int wv = tid >> 6, lane = tid & 63;

  __shared__ float sh[4 * 256];
  __shared__ float shq[4];
  __shared__ float dss[NC], dtt[NC], dst[NC];
  __shared__ float dcen[28];
  __shared__ float shred[4];

  int*   cnt_s = (int*)(ws + OFF_CNT_S);
  int*   cnt_t = (int*)(ws + OFF_CNT_T);
  float* sw    = (float*)(ws + OFF_SW);
  float* sqs   = (float*)(ws + OFF_SQS);
  float* sqt   = (float*)(ws + OFF_SQT);
  float* invbw = (float*)(ws + OFF_INVBW);
  float* scc   = (float*)(ws + OFF_SCC);
  float* snn   = (float*)(ws + OFF_SNN);
  float* scn   = (float*)(ws + OFF_SCN);
  float* vs    = (float*)(ws + OFF_VS);
  float* vt    = (float*)(ws + OFF_VT);
  int*   idx_s = (int*)(ws + OFF_IDX_S);
  int*   idx_t = (int*)(ws + OFF_IDX_T);
  float* wt    = (float*)(ws + OFF_WT);
  float* qnS   = (float*)(ws + OFF_QNS);
  float* qnT   = (float*)(ws + OFF_QNT);

  // ============ Phase A: lists + zeroing ============
  if (bx < 16) {
    if (wv == 0) {
      int c = bx & 7;
      if (bx < 8) {                       // clean list for class c
        int lv[32];
#pragma unroll
        for (int it = 0; it < 32; ++it) lv[it] = clab[it * 64 + lane];
        int base = 0;
#pragma unroll
        for (int it = 0; it < 32; ++it) {
          bool m = (lv[it] == c);
          unsigned long long msk = __ballot(m);
          int pos = __popcll(msk & ((1ull << lane) - 1ull));
          if (m) idx_s[c * NN + base + pos] = it * 64 + lane;
          base += __popcll(msk);
        }
        if (lane == 0) cnt_s[c] = base;
      } else {                            // noisy list for class c
        int lv[32]; float mv[32], sv[32];
#pragma unroll
        for (int it = 0; it < 32; ++it) {
          int i = it * 64 + lane;
          lv[it] = nlab[i]; mv[it] = nmask[i]; sv[it] = nscore[i];
        }
        int base = 0; float swa = 0.f;
#pragma unroll
        for (int it = 0; it < 32; ++it) {
          bool m = (lv[it] == c) && (mv[it] > 0.5f);
          unsigned long long msk = __ballot(m);
          int pos = __popcll(msk & ((1ull << lane) - 1ull));
          if (m) { idx_t[c * NN + base + pos] = it * 64 + lane;
                   wt[c * NN + base + pos] = sv[it]; swa += sv[it]; }
          base += __popcll(msk);
        }
        swa = wred64(swa);
        if (lane == 0) { cnt_t[c] = base; sw[c] = swa; }
      }
    }
  } else if (bx < 32) {
    vs[(bx - 16) * 256 + tid] = 0.f;      // zeroes vs+vt (4096 f32 contiguous)
  } else if (bx == 32) {
    if (tid < 8) { sqs[tid] = 0.f; sqt[tid] = 0.f; }
  }
  grid.sync();

  // ============ Phase B: moments + per-position bf16 norms ============
  {
    int c = bx >> 5, chunk = bx & 31;
    int d4 = lane * 4;
    // clean
    {
      float vx = 0.f, vy = 0.f, vz = 0.f, vw = 0.f, qa = 0.f;
      int ns = cnt_s[c];
      for (int m = chunk + 32 * wv; m < ns; m += 128) {
        int item = idx_s[c * NN + m];
        float4 v = *(const float4*)&cfeat[item * DD + d4];
        vx += v.x; vy += v.y; vz += v.z; vw += v.w;
        qa += v.x * v.x + v.y * v.y + v.z * v.z + v.w * v.w;
        float rx = rbf(v.x), ry = rbf(v.y), rz = rbf(v.z), rw = rbf(v.w);
        float qr = wred64(rx * rx + ry * ry + rz * rz + rw * rw);
        if (lane == 0) qnS[c * NN + m] = qr;
      }
      sh[wv * 256 + d4 + 0] = vx; sh[wv * 256 + d4 + 1] = vy;
      sh[wv * 256 + d4 + 2] = vz; sh[wv * 256 + d4 + 3] = vw;
      qa = wred64(qa);
      if (lane == 0) shq[wv] = qa;
      __syncthreads();
      float s = sh[tid] + sh[256 + tid] + sh[512 + tid] + sh[768 + tid];
      atomicAdd(&vs[c * DD + tid], s);
      if (tid == 0) atomicAdd(&sqs[c], shq[0] + shq[1] + shq[2] + shq[3]);
      __syncthreads();
    }
    // noisy
    {
      float vx = 0.f, vy = 0.f, vz = 0.f, vw = 0.f, qa = 0.f;
      int nt = cnt_t[c];
      for (int m = chunk + 32 * wv; m < nt; m += 128) {
        int item = idx_t[c * NN + m];
        float4 v = *(const float4*)&nfeat[item * DD + d4];
        vx += v.x; vy += v.y; vz += v.z; vw += v.w;
        qa += v.x * v.x + v.y * v.y + v.z * v.z + v.w * v.w;
        float rx = rbf(v.x), ry = rbf(v.y), rz = rbf(v.z), rw = rbf(v.w);
        float qr = wred64(rx * rx + ry * ry + rz * rz + rw * rw);
        if (lane == 0) qnT[c * NN + m] = qr;
      }
      sh[wv * 256 + d4 + 0] = vx; sh[wv * 256 + d4 + 1] = vy;
      sh[wv * 256 + d4 + 2] = vz; sh[wv * 256 + d4 + 3] = vw;
      qa = wred64(qa);
      if (lane == 0) shq[wv] = qa;
      __syncthreads();
      float s = sh[tid] + sh[256 + tid] + sh[512 + tid] + sh[768 + tid];
      atomicAdd(&vt[c * DD + tid], s);
      if (tid == 0) atomicAdd(&sqt[c], shq[0] + shq[1] + shq[2] + shq[3]);
    }
  }
  grid.sync();

  // ============ Phase C: bandwidths, scales, base loss (block 0) ============
  if (bx == 0) {
    for (int t = wv; t < 24; t += 4) {
      int c = t / 3, kind = t - c * 3;
      const float* xa = (kind == 1) ? (vt + c * DD) : (vs + c * DD);
      const float* ya = (kind == 0) ? (vs + c * DD) : (vt + c * DD);
      float4 x = *(const float4*)&xa[lane * 4];
      float4 y = *(const float4*)&ya[lane * 4];
      float s = wred64(x.x * y.x + x.y * y.y + x.z * y.z + x.w * y.w);
      if (lane == 0) {
        if (kind == 0) dss[c] = s; else if (kind == 1) dtt[c] = s; else dst[c] = s;
      }
    }
    for (int t = wv; t < 28; t += 4) {
      int a = 0, r = t;
      while (r >= 7 - a) { r -= 7 - a; ++a; }
      int b = a + 1 + r;
      float ima = 1.f / fmaxf((float)cnt_t[a], 1.f);
      float imb = 1.f / fmaxf((float)cnt_t[b], 1.f);
      float4 x = *(const float4*)&vt[a * DD + lane * 4];
      float4 y = *(const float4*)&vt[b * DD + lane * 4];
      float dx = x.x * ima - y.x * imb, dy = x.y * ima - y.y * imb;
      float dz = x.z * ima - y.z * imb, dw = x.w * ima - y.w * imb;
      float s = wred64(dx * dx + dy * dy + dz * dz + dw * dw);
      if (lane == 0) dcen[t] = sqrtf(fmaxf(s, 1e-12f));
    }
    __syncthreads();
    if (tid == 0) {
      int nvalid = 0;
      for (int c = 0; c < NC; ++c) nvalid += (cnt_t[c] > 0);
      float sumD = 0.f; int np = 0; int p = 0;
      for (int a = 0; a < NC; ++a)
        for (int b = a + 1; b < NC; ++b) {
          if (cnt_t[a] > 0 && cnt_t[b] > 0) { sumD += dcen[p]; ++np; }
          ++p;
        }
      float repl = (nvalid > 1) ? (-sumD / fmaxf((float)np, 1.f)) : 0.f;
      float meanw = 0.f;
      for (int c = 0; c < NC; ++c) meanw += cw[c];
      meanw *= (1.f / NC);
      float base = 0.f;
      for (int c = 0; c < NC; ++c) {
        float ns = (float)cnt_s[c], nt = (float)cnt_t[c];
        float n = ns + nt;
        float sumL2 = 2.f * ns * sqs[c] - 2.f * dss[c]
                    + 2.f * nt * sqt[c] - 2.f * dtt[c]
                    + 2.f * (nt * sqs[c] + ns * sqt[c] - 2.f * dst[c]);
        float bw0 = sumL2 / fmaxf(n * n - n, 1.f) * 0.25f;  // /half, half=4
        float mul = 1.f;
        for (int k = 0; k < 5; ++k) {
          invbw[c * 5 + k] = 1.f / (bw0 * mul + 1e-8f);
          mul *= 2.f;
        }
        float attn = expf(meanw - cw[c]);                    // LAMBDA = 1
        float coef = (cnt_s[c] >= 2 && cnt_t[c] >= 2) ? attn : 0.f;
        float swc = sw[c];
        scc[c] = coef / (ns * ns + 1e-8f);
        snn[c] = coef / (swc * swc + 1e-8f);
        scn[c] = -2.f * coef / (ns * swc + 1e-8f);
        float mx = fmaxf(nt, 1.f);
        float compact = (sqt[c] - 2.f * dtt[c] / mx + nt * dtt[c] / (mx * mx)) / mx;
        base += coef * (0.1f * compact + 0.01f * repl);
      }
      out[0] = base;
    }
  }
  grid.sync();

  // ============ Phase D: MFMA pairwise tiles, grid-strided ============
  float thr_acc = 0.f;
  for (int t = bx; t < 1536; t += 256) {
    int type  = t >> 9;
    int c     = (t >> 6) & 7;
    int rtile = (t >> 3) & 7;
    int ctile = t & 7;
    if (type <= 1 && ctile < rtile) continue;   // symmetric: upper only

    const int* pa; const int* pb;
    const float* fa; const float* fb;
    const float* qa_; const float* qb_;
    const float* wa = nullptr; const float* wb = nullptr;
    int na, nb; float scale;
    if (type == 0) {
      pa = idx_s + c * NN; pb = pa; na = nb = cnt_s[c];
      fa = cfeat; fb = cfeat; qa_ = qnS + c * NN; qb_ = qa_; scale = scc[c];
    } else if (type == 1) {
      pa = idx_t + c * NN; pb = pa; na = nb = cnt_t[c];
      fa = nfeat; fb = nfeat; qa_ = qnT + c * NN; qb_ = qa_;
      wa = wt + c * NN; wb = wa; scale = snn[c];
    } else {
      pa = idx_s + c * NN; na = cnt_s[c];
      pb = idx_t + c * NN; nb = cnt_t[c];
      fa = cfeat; fb = nfeat; qa_ = qnS + c * NN; qb_ = qnT + c * NN;
      wb = wt + c * NN; scale = scn[c];
    }
    int rbase = rtile * 32, cbase = ctile * 32;
    if (scale == 0.f || rbase >= na || cbase >= nb) continue;
    float factor = (type <= 1 && ctile > rtile) ? 2.f : 1.f;

    float ib0 = invbw[c * 5 + 0], ib1 = invbw[c * 5 + 1], ib2 = invbw[c * 5 + 2];
    float ib3 = invbw[c * 5 + 3], ib4 = invbw[c * 5 + 4];

    int sr = (wv >> 1) * 16, sc2 = (wv & 1) * 16;
    int posA = rbase + sr + (lane & 15);
    int posB = cbase + sc2 + (lane & 15);
    int pAc = posA < na ? posA : (na - 1);
    int pBc = posB < nb ? posB : (nb - 1);
    const float* rowA = fa + (long)pa[pAc] * DD + (lane >> 4) * 8;
    const float* rowB = fb + (long)pb[pBc] * DD + (lane >> 4) * 8;

    f32x4 acc = {0.f, 0.f, 0.f, 0.f};
#pragma unroll
    for (int ks = 0; ks < 8; ++ks) {
      float4 a0 = *(const float4*)(rowA + ks * 32);
      float4 a1 = *(const float4*)(rowA + ks * 32 + 4);
      float4 b0 = *(const float4*)(rowB + ks * 32);
      float4 b1 = *(const float4*)(rowB + ks * 32 + 4);
      bf16x8 af, bf;
      af[0] = f2bf(a0.x); af[1] = f2bf(a0.y); af[2] = f2bf(a0.z); af[3] = f2bf(a0.w);
      af[4] = f2bf(a1.x); af[5] = f2bf(a1.y); af[6] = f2bf(a1.z); af[7] = f2bf(a1.w);
      bf[0] = f2bf(b0.x); bf[1] = f2bf(b0.y); bf[2] = f2bf(b0.z); bf[3] = f2bf(b0.w);
      bf[4] = f2bf(b1.x); bf[5] = f2bf(b1.y); bf[6] = f2bf(b1.z); bf[7] = f2bf(b1.w);
      acc = __builtin_amdgcn_mfma_f32_16x16x32_bf16(af, bf, acc, 0, 0, 0);
    }

    bool jval = (posB < nb);
    float knj = qb_[pBc];
    float wj = (type == 0) ? 1.f : wb[pBc];
    int rowbase = rbase + sr + ((lane >> 4) << 2);          // 16B-aligned
    f32x4 qA4 = *(const f32x4*)&qa_[rowbase];
    f32x4 wA4 = {1.f, 1.f, 1.f, 1.f};
    if (type == 1) wA4 = *(const f32x4*)&wa[rowbase];

    float partial = 0.f;
#pragma unroll
    for (int r = 0; r < 4; ++r) {
      int ipos = rowbase + r;
      bool val = jval && (ipos < na);
      float d2 = fmaxf(qA4[r] + knj - 2.f * acc[r], 0.f);
      float e = __expf(-d2 * ib0) + __expf(-d2 * ib1) + __expf(-d2 * ib2)
              + __expf(-d2 * ib3) + __expf(-d2 * ib4);
      float wgt = (type == 1) ? wA4[r] * wj : wj;
      partial += val ? wgt * e : 0.f;
    }
    thr_acc += scale * factor * partial;
  }
  thr_acc = wred64(thr_acc);
  if (lane == 0) shred[wv] = thr_acc;
  __syncthreads();
  if (tid == 0) {
    float tot = shred[0] + shred[1] + shred[2] + shred[3];
    if (tot != 0.f) atomicAdd(out, tot);
  }
}

extern "C" void kernel_launch(void* const* d_in, const int* in_sizes, int n_in,
                              void* d_out, int out_size, void* d_ws, size_t ws_size,
                              hipStream_t stream) {
  const float* cfeat  = (const float*)d_in[0];
  const float* nfeat  = (const float*)d_in[1];
  const int*   clab   = (const int*)d_in[2];
  const int*   nlab   = (const int*)d_in[3];
  const float* nmask  = (const float*)d_in[4];
  const float* nscore = (const float*)d_in[5];
  const float* cw     = (const float*)d_in[6];
  float* out = (float*)d_out;
  char* ws = (char*)d_ws;

  void* args[] = { (void*)&cfeat, (void*)&nfeat, (void*)&clab, (void*)&nlab,
                   (void*)&nmask, (void*)&nscore, (void*)&cw, (void*)&ws,
                   (void*)&out };
  hipLaunchCooperativeKernel((const void*)ecda_all, dim3(256), dim3(256),
                             args, 0, stream);
}

// Round 5
// 52.533 us; speedup vs baseline: 2.5240x; 2.5240x over previous
//
#include <hip/hip_runtime.h>
#include <math.h>

// ECDA loss, 2-kernel formulation (no grid.sync — kernel boundary only).
// K_prep: lists + per-item norms + moments (all block-independent).
// K_pairs: per-tile MFMA with redundant per-block prologue; block 1536 = finale.

static constexpr int NC = 8;
static constexpr int NN = 2048;
static constexpr int DD = 256;

// workspace byte offsets
static constexpr int OFF_CNT_S = 0;        // 8 int
static constexpr int OFF_CNT_T = 64;       // 8 int
static constexpr int OFF_SW    = 128;      // 8 f32
static constexpr int OFF_VS    = 4096;     // 8*256 f32 (plain stores)
static constexpr int OFF_VT    = 12288;    // 8*256 f32
static constexpr int OFF_IDX_S = 32768;    // 8*2048 int
static constexpr int OFF_IDX_T = 98304;    // 8*2048 int
static constexpr int OFF_WT    = 163840;   // 8*2048 f32
static constexpr int OFF_QRAW  = 229376;   // 4096 f32: raw norms (clean 0..2047, noisy 2048..)
static constexpr int OFF_QBF   = 245760;   // 4096 f32: bf16-rounded norms
// total 256 KB

typedef __attribute__((ext_vector_type(8))) short bf16x8;
typedef __attribute__((ext_vector_type(4))) float f32x4;

__device__ inline float wred64(float v) {
  for (int o = 32; o > 0; o >>= 1) v += __shfl_xor(v, o, 64);
  return v;
}
__device__ inline short f2bf(float x) {
  unsigned u = __float_as_uint(x);
  return (short)((u + 0x7fffu + ((u >> 16) & 1u)) >> 16);
}
__device__ inline float rbf(float x) {
  unsigned u = __float_as_uint(x);
  u = (u + 0x7fffu + ((u >> 16) & 1u)) & 0xffff0000u;
  return __uint_as_float(u);
}

// ---------------- K_prep: 148 blocks ----------------
// blocks 0-3: ballot lists (wave-task = bx*4+wv: 0-7 clean c, 8-15 noisy c)
// blocks 4-131: per-item norms, 32 rows each (4096 rows total)
// blocks 132-147: moments vs/vt, one (class,type) per block, plain stores
__global__ __launch_bounds__(256) void ecda_prep(
    const float* __restrict__ cfeat, const float* __restrict__ nfeat,
    const int* __restrict__ clab, const int* __restrict__ nlab,
    const float* __restrict__ nmask, const float* __restrict__ nscore,
    char* __restrict__ ws, float* __restrict__ out) {
  int tid = threadIdx.x, bx = blockIdx.x;
  int wv = tid >> 6, lane = tid & 63;
  int*   cnt_s = (int*)(ws + OFF_CNT_S);
  int*   cnt_t = (int*)(ws + OFF_CNT_T);
  float* sw    = (float*)(ws + OFF_SW);
  float* vs    = (float*)(ws + OFF_VS);
  float* vt    = (float*)(ws + OFF_VT);
  int*   idx_s = (int*)(ws + OFF_IDX_S);
  int*   idx_t = (int*)(ws + OFF_IDX_T);
  float* wt    = (float*)(ws + OFF_WT);
  float* qraw  = (float*)(ws + OFF_QRAW);
  float* qbf   = (float*)(ws + OFF_QBF);
  __shared__ float accm[4][256];

  if (bx < 4) {
    if (bx == 0 && tid == 0) out[0] = 0.f;
    int task = bx * 4 + wv, c = task & 7;
    if (task < 8) {                       // clean list class c
      int lv[32];
#pragma unroll
      for (int it = 0; it < 32; ++it) lv[it] = clab[it * 64 + lane];
      int base = 0;
#pragma unroll
      for (int it = 0; it < 32; ++it) {
        bool m = (lv[it] == c);
        unsigned long long msk = __ballot(m);
        int pos = __popcll(msk & ((1ull << lane) - 1ull));
        if (m) idx_s[c * NN + base + pos] = it * 64 + lane;
        base += __popcll(msk);
      }
      if (lane == 0) cnt_s[c] = base;
    } else {                              // noisy list class c
      int lv[32]; float mv[32], sv[32];
#pragma unroll
      for (int it = 0; it < 32; ++it) {
        int i = it * 64 + lane;
        lv[it] = nlab[i]; mv[it] = nmask[i]; sv[it] = nscore[i];
      }
      int base = 0; float swa = 0.f;
#pragma unroll
      for (int it = 0; it < 32; ++it) {
        bool m = (lv[it] == c) && (mv[it] > 0.5f);
        unsigned long long msk = __ballot(m);
        int pos = __popcll(msk & ((1ull << lane) - 1ull));
        if (m) { idx_t[c * NN + base + pos] = it * 64 + lane;
                 wt[c * NN + base + pos] = sv[it]; swa += sv[it]; }
        base += __popcll(msk);
      }
      swa = wred64(swa);
      if (lane == 0) { cnt_t[c] = base; sw[c] = swa; }
    }
  } else if (bx < 132) {                  // per-item norms (raw + bf16-rounded)
    int g0 = (bx - 4) * 32 + wv * 8;
    for (int r = 0; r < 8; ++r) {
      int g = g0 + r;
      const float* rowp = (g < NN) ? (cfeat + (size_t)g * DD)
                                   : (nfeat + (size_t)(g - NN) * DD);
      float4 v = *(const float4*)&rowp[lane * 4];
      float raw = v.x * v.x + v.y * v.y + v.z * v.z + v.w * v.w;
      float rx = rbf(v.x), ry = rbf(v.y), rz = rbf(v.z), rw = rbf(v.w);
      float rq = rx * rx + ry * ry + rz * rz + rw * rw;
      raw = wred64(raw); rq = wred64(rq);
      if (lane == 0) { qraw[g] = raw; qbf[g] = rq; }
    }
  } else if (bx < 148) {                  // moments: one (class,type) per block
    int idx = bx - 132, c = idx & 7, typ = idx >> 3;
    const float* feats = typ ? nfeat : cfeat;
    const int* labs = typ ? nlab : clab;
    float ax = 0.f, ay = 0.f, az = 0.f, aw = 0.f;
    for (int ch = 0; ch < 8; ++ch) {      // wave scans its 512 rows in 64-chunks
      int i0 = wv * 512 + ch * 64;
      int lb = labs[i0 + lane];
      bool m = (lb == c);
      if (typ) m = m && (nmask[i0 + lane] > 0.5f);
      unsigned long long msk = __ballot(m);
      while (msk) {
        int j = __builtin_ctzll(msk); msk &= msk - 1;
        float4 v = *(const float4*)&feats[(size_t)(i0 + j) * DD + lane * 4];
        ax += v.x; ay += v.y; az += v.z; aw += v.w;
      }
    }
    accm[wv][lane * 4 + 0] = ax; accm[wv][lane * 4 + 1] = ay;
    accm[wv][lane * 4 + 2] = az; accm[wv][lane * 4 + 3] = aw;
    __syncthreads();
    float s = accm[0][tid] + accm[1][tid] + accm[2][tid] + accm[3][tid];
    (typ ? vt : vs)[c * DD + tid] = s;
  }
}

// ---------------- K_pairs: 1537 blocks ----------------
__global__ __launch_bounds__(256) void ecda_pairs(
    const float* __restrict__ cfeat, const float* __restrict__ nfeat,
    const float* __restrict__ cw, char* __restrict__ ws,
    float* __restrict__ out) {
  __shared__ float shred[4];
  __shared__ float pl[8];        // 0:sqs 1:sqt 2:dss 3:dtt 4:dst
  __shared__ float plinv[5];
  __shared__ float plscale;
  __shared__ float sqsA[8], sqtA[8], dssA[8], dttA[8], dstA[8], dcen[28];

  int tid = threadIdx.x, bx = blockIdx.x;
  int wv = tid >> 6, lane = tid & 63;
  const int* cnt_s = (const int*)(ws + OFF_CNT_S);
  const int* cnt_t = (const int*)(ws + OFF_CNT_T);
  const float* sw  = (const float*)(ws + OFF_SW);
  const float* vs  = (const float*)(ws + OFF_VS);
  const float* vt  = (const float*)(ws + OFF_VT);
  const int* idx_s = (const int*)(ws + OFF_IDX_S);
  const int* idx_t = (const int*)(ws + OFF_IDX_T);
  const float* wt  = (const float*)(ws + OFF_WT);
  const float* qraw = (const float*)(ws + OFF_QRAW);
  const float* qbf  = (const float*)(ws + OFF_QBF);
  const float* qrawC = qraw;      const float* qrawN = qraw + NN;
  const float* qbfC  = qbf;       const float* qbfN  = qbf + NN;

  if (bx == 1536) {                       // finale: repulsion + compact + base
    for (int t = wv; t < 16; t += 4) {    // sqs/sqt all classes (raw-norm gathers)
      int c = t & 7, isT = t >> 3;
      int n = isT ? cnt_t[c] : cnt_s[c];
      const int* il = (isT ? idx_t : idx_s) + c * NN;
      const float* qr = isT ? qrawN : qrawC;
      float s = 0.f;
      for (int m = lane; m < n; m += 64) s += qr[il[m]];
      s = wred64(s);
      if (lane == 0) { if (isT) sqtA[c] = s; else sqsA[c] = s; }
    }
    for (int t = wv; t < 24; t += 4) {    // dss/dtt/dst
      int c = t / 3, kind = t - c * 3;
      const float* xa = (kind == 1) ? (vt + c * DD) : (vs + c * DD);
      const float* ya = (kind == 0) ? (vs + c * DD) : (vt + c * DD);
      float4 x = *(const float4*)&xa[lane * 4];
      float4 y = *(const float4*)&ya[lane * 4];
      float s = wred64(x.x * y.x + x.y * y.y + x.z * y.z + x.w * y.w);
      if (lane == 0) {
        if (kind == 0) dssA[c] = s; else if (kind == 1) dttA[c] = s; else dstA[c] = s;
      }
    }
    for (int t = wv; t < 28; t += 4) {    // centroid distances
      int a = 0, r = t;
      while (r >= 7 - a) { r -= 7 - a; ++a; }
      int b = a + 1 + r;
      float ima = 1.f / fmaxf((float)cnt_t[a], 1.f);
      float imb = 1.f / fmaxf((float)cnt_t[b], 1.f);
      float4 x = *(const float4*)&vt[a * DD + lane * 4];
      float4 y = *(const float4*)&vt[b * DD + lane * 4];
      float dx = x.x * ima - y.x * imb, dy = x.y * ima - y.y * imb;
      float dz = x.z * ima - y.z * imb, dw = x.w * ima - y.w * imb;
      float s = wred64(dx * dx + dy * dy + dz * dz + dw * dw);
      if (lane == 0) dcen[t] = sqrtf(fmaxf(s, 1e-12f));
    }
    __syncthreads();
    if (tid == 0) {
      int nvalid = 0;
      for (int c = 0; c < NC; ++c) nvalid += (cnt_t[c] > 0);
      float sumD = 0.f; int np = 0; int p = 0;
      for (int a = 0; a < NC; ++a)
        for (int b = a + 1; b < NC; ++b) {
          if (cnt_t[a] > 0 && cnt_t[b] > 0) { sumD += dcen[p]; ++np; }
          ++p;
        }
      float repl = (nvalid > 1) ? (-sumD / fmaxf((float)np, 1.f)) : 0.f;
      float meanw = 0.f;
      for (int c = 0; c < NC; ++c) meanw += cw[c];
      meanw *= (1.f / NC);
      float base = 0.f;
      for (int c = 0; c < NC; ++c) {
        float nt = (float)cnt_t[c];
        float coef = (cnt_s[c] >= 2 && cnt_t[c] >= 2) ? expf(meanw - cw[c]) : 0.f;
        float mx = fmaxf(nt, 1.f);
        float compact = (sqtA[c] - 2.f * dttA[c] / mx + nt * dttA[c] / (mx * mx)) / mx;
        base += coef * (0.1f * compact + 0.01f * repl);
      }
      atomicAdd(out, base);
    }
    return;
  }

  // -------- tile block --------
  int t = bx;
  int type  = t >> 9;
  int c     = (t >> 6) & 7;
  int rtile = (t >> 3) & 7;
  int ctile = t & 7;
  if (type <= 1 && ctile < rtile) return;
  int nsc = cnt_s[c], ntc = cnt_t[c];
  if (nsc < 2 || ntc < 2) return;

  const int* pa; const int* pb;
  const float* fa; const float* fb;
  const float* qaB; const float* qbB;
  const float* wtc = wt + c * NN;
  int na, nb;
  if (type == 0) {
    pa = idx_s + c * NN; pb = pa; na = nb = nsc;
    fa = cfeat; fb = cfeat; qaB = qbfC; qbB = qbfC;
  } else if (type == 1) {
    pa = idx_t + c * NN; pb = pa; na = nb = ntc;
    fa = nfeat; fb = nfeat; qaB = qbfN; qbB = qbfN;
  } else {
    pa = idx_s + c * NN; na = nsc;
    pb = idx_t + c * NN; nb = ntc;
    fa = cfeat; fb = nfeat; qaB = qbfC; qbB = qbfN;
  }
  int rbase = rtile * 32, cbase = ctile * 32;
  if (rbase >= na || cbase >= nb) return;

  // -------- per-block prologue: class-c bandwidth + scale --------
  if (wv == 0) {
    float s = 0.f;
    for (int m = lane; m < nsc; m += 64) s += qrawC[idx_s[c * NN + m]];
    s = wred64(s); if (lane == 0) pl[0] = s;
    float4 x = *(const float4*)&vs[c * DD + lane * 4];
    float4 y = *(const float4*)&vt[c * DD + lane * 4];
    float d = wred64(x.x * y.x + x.y * y.y + x.z * y.z + x.w * y.w);
    if (lane == 0) pl[4] = d;
  } else if (wv == 1) {
    float s = 0.f;
    for (int m = lane; m < ntc; m += 64) s += qrawN[idx_t[c * NN + m]];
    s = wred64(s); if (lane == 0) pl[1] = s;
  } else if (wv == 2) {
    float4 x = *(const float4*)&vs[c * DD + lane * 4];
    float d = wred64(x.x * x.x + x.y * x.y + x.z * x.z + x.w * x.w);
    if (lane == 0) pl[2] = d;
  } else {
    float4 x = *(const float4*)&vt[c * DD + lane * 4];
    float d = wred64(x.x * x.x + x.y * x.y + x.z * x.z + x.w * x.w);
    if (lane == 0) pl[3] = d;
  }
  __syncthreads();
  if (tid == 0) {
    float ns = (float)nsc, nt = (float)ntc, n = ns + nt;
    float sumL2 = 2.f * ns * pl[0] - 2.f * pl[2]
                + 2.f * nt * pl[1] - 2.f * pl[3]
                + 2.f * (nt * pl[0] + ns * pl[1] - 2.f * pl[4]);
    float bw0 = sumL2 / fmaxf(n * n - n, 1.f) * 0.25f;   // /half, half=4
    float mul = 1.f;
    for (int k = 0; k < 5; ++k) { plinv[k] = 1.f / (bw0 * mul + 1e-8f); mul *= 2.f; }
    float meanw = 0.f;
    for (int c2 = 0; c2 < NC; ++c2) meanw += cw[c2];
    meanw *= (1.f / NC);
    float attn = expf(meanw - cw[c]);
    float swc = sw[c];
    float scale = (type == 0) ? attn / (ns * ns + 1e-8f)
                : (type == 1) ? attn / (swc * swc + 1e-8f)
                              : -2.f * attn / (ns * swc + 1e-8f);
    float factor = (type <= 1 && ctile > rtile) ? 2.f : 1.f;
    plscale = scale * factor;
  }
  __syncthreads();
  float ib0 = plinv[0], ib1 = plinv[1], ib2 = plinv[2];
  float ib3 = plinv[3], ib4 = plinv[4];

  // -------- MFMA tile body --------
  int sr = (wv >> 1) * 16, sc2 = (wv & 1) * 16;
  int posA = rbase + sr + (lane & 15);
  int posB = cbase + sc2 + (lane & 15);
  int pAc = posA < na ? posA : (na - 1);
  int pBc = posB < nb ? posB : (nb - 1);
  int ia = pa[pAc], ibI = pb[pBc];
  const float* rowA = fa + (size_t)ia * DD + (lane >> 4) * 8;
  const float* rowB = fb + (size_t)ibI * DD + (lane >> 4) * 8;

  f32x4 acc = {0.f, 0.f, 0.f, 0.f};
#pragma unroll
  for (int ks = 0; ks < 8; ++ks) {
    float4 a0 = *(const float4*)(rowA + ks * 32);
    float4 a1 = *(const float4*)(rowA + ks * 32 + 4);
    float4 b0 = *(const float4*)(rowB + ks * 32);
    float4 b1 = *(const float4*)(rowB + ks * 32 + 4);
    bf16x8 af, bf;
    af[0] = f2bf(a0.x); af[1] = f2bf(a0.y); af[2] = f2bf(a0.z); af[3] = f2bf(a0.w);
    af[4] = f2bf(a1.x); af[5] = f2bf(a1.y); af[6] = f2bf(a1.z); af[7] = f2bf(a1.w);
    bf[0] = f2bf(b0.x); bf[1] = f2bf(b0.y); bf[2] = f2bf(b0.z); bf[3] = f2bf(b0.w);
    bf[4] = f2bf(b1.x); bf[5] = f2bf(b1.y); bf[6] = f2bf(b1.z); bf[7] = f2bf(b1.w);
    acc = __builtin_amdgcn_mfma_f32_16x16x32_bf16(af, bf, acc, 0, 0, 0);
  }

  // epilogue: lane holds D[row][col], col = cbase+sc2+(lane&15), row = rowbase+r
  bool jval = (posB < nb);
  float knj = qbB[ibI];
  float wj = (type == 0) ? 1.f : wtc[pBc];
  int rowbase = rbase + sr + ((lane >> 4) << 2);
  float partial = 0.f;
#pragma unroll
  for (int r = 0; r < 4; ++r) {
    int ip = rowbase + r;
    bool val = jval && (ip < na);
    int ipc = ip < na ? ip : (na - 1);
    int iar = pa[ipc];                       // clamped: ws may hold garbage ints
    float qA = qaB[iar];
    float wA = (type == 1) ? wtc[ipc] : 1.f;
    float d2 = fmaxf(qA + knj - 2.f * acc[r], 0.f);
    float e = __expf(-d2 * ib0) + __expf(-d2 * ib1) + __expf(-d2 * ib2)
            + __expf(-d2 * ib3) + __expf(-d2 * ib4);
    partial += val ? wA * wj * e : 0.f;
  }
  partial = wred64(partial);
  if (lane == 0) shred[wv] = partial;
  __syncthreads();
  if (tid == 0) {
    float tot = shred[0] + shred[1] + shred[2] + shred[3];
    atomicAdd(out, plscale * tot);
  }
}

extern "C" void kernel_launch(void* const* d_in, const int* in_sizes, int n_in,
                              void* d_out, int out_size, void* d_ws, size_t ws_size,
                              hipStream_t stream) {
  const float* cfeat  = (const float*)d_in[0];
  const float* nfeat  = (const float*)d_in[1];
  const int*   clab   = (const int*)d_in[2];
  const int*   nlab   = (const int*)d_in[3];
  const float* nmask  = (const float*)d_in[4];
  const float* nscore = (const float*)d_in[5];
  const float* cw     = (const float*)d_in[6];
  float* out = (float*)d_out;
  char* ws = (char*)d_ws;

  ecda_prep<<<148, 256, 0, stream>>>(cfeat, nfeat, clab, nlab, nmask, nscore,
                                     ws, out);
  ecda_pairs<<<1537, 256, 0, stream>>>(cfeat, nfeat, cw, ws, out);
}

// Round 6
// 35.783 us; speedup vs baseline: 3.7055x; 1.4681x over previous
//
#include <hip/hip_runtime.h>
#include <math.h>

// ECDA loss, 3-kernel packed formulation.
// K1 ecda_pack: per-(class,type,chunk) blocks ballot-scan labels, pack class
//   rows into compacted bf16 matrices + norms + weights + partial moments.
// K2 ecda_scalars: per-class reduction of partials -> all per-class scalars.
// K3 ecda_pairs: pure MFMA pair tiles over packed bf16 + finale block.

static constexpr int NC = 8;
static constexpr int NN = 2048;
static constexpr int DD = 256;

// workspace byte offsets
static constexpr int OFF_CNT_S = 0;         // 8 int
static constexpr int OFF_CNT_T = 64;        // 8 int
static constexpr int OFF_SW    = 128;       // 8 f32
static constexpr int OFF_COEF  = 192;       // 8 f32 (attn coef, gated)
static constexpr int OFF_CCOMP = 256;       // 8 f32 (coef*0.1*compact)
static constexpr int OFF_INVBW = 320;       // 8*5 f32
static constexpr int OFF_SCC   = 512;       // 8 f32
static constexpr int OFF_SNN   = 576;       // 8 f32
static constexpr int OFF_SCN   = 640;       // 8 f32
static constexpr int OFF_SQSP  = 1024;      // 8*8 f32 partial raw-norm sums (clean)
static constexpr int OFF_SQTP  = 1280;      // 8*8 f32 (noisy)
static constexpr int OFF_VSP   = 4096;      // 8c*8ch*256 f32 partial moments (clean)
static constexpr int OFF_VTP   = 69632;     // same (noisy)
static constexpr int OFF_VS    = 135168;    // 8*256 f32 reduced
static constexpr int OFF_VT    = 143360;    // 8*256 f32
static constexpr int OFF_QBFS  = 151552;    // 8*2048 f32 bf16-norms by position (clean)
static constexpr int OFF_QBFT  = 217088;    // 8*2048 f32 (noisy)
static constexpr int OFF_WTP   = 282624;    // 8*2048 f32 weights by position
static constexpr int OFF_PKS   = 348160;    // 8*2048*256 bf16 packed clean (8 MB)
static constexpr int OFF_PKT   = 8736768;   // packed noisy (8 MB)
// total ~17 MB (<268 MB ws)

typedef __attribute__((ext_vector_type(8))) short bf16x8;
typedef __attribute__((ext_vector_type(4))) float f32x4;

__device__ inline float wred64(float v) {
  for (int o = 32; o > 0; o >>= 1) v += __shfl_xor(v, o, 64);
  return v;
}
__device__ inline float brs256(float v, float* sh4) {
  for (int o = 32; o > 0; o >>= 1) v += __shfl_xor(v, o, 64);
  int w = threadIdx.x >> 6, ln = threadIdx.x & 63;
  __syncthreads();
  if (ln == 0) sh4[w] = v;
  __syncthreads();
  float r = 0.f;
  if (threadIdx.x == 0) r = sh4[0] + sh4[1] + sh4[2] + sh4[3];
  return r;
}

// ---------------- K1: 128 blocks = typ(2) x class(8) x chunk(8) ----------------
__global__ __launch_bounds__(256) void ecda_pack(
    const float* __restrict__ cfeat, const float* __restrict__ nfeat,
    const int* __restrict__ clab, const int* __restrict__ nlab,
    const float* __restrict__ nmask, const float* __restrict__ nscore,
    char* __restrict__ ws, float* __restrict__ out) {
  __shared__ int   ls_idx[NN];
  __shared__ float ls_wt[NN];
  __shared__ int   ls_cntw[4];
  __shared__ float ls_mom[4][256];
  __shared__ float ls_sq[4];
  __shared__ float sh4[4];
  int tid = threadIdx.x, bx = blockIdx.x;
  int wv = tid >> 6, lane = tid & 63;
  int typ = bx >> 6, c = (bx >> 3) & 7, chunk = bx & 7;

  if (bx == 0 && tid == 0) out[0] = 0.f;

  const int* labs = typ ? nlab : clab;
  const float* feats = typ ? nfeat : cfeat;

  // pass 1: per-wave match counts over its 512 rows
  int rb = wv * 512;
  int lv[8]; float mv[8], sv[8];
#pragma unroll
  for (int it = 0; it < 8; ++it) {
    int i = rb + it * 64 + lane;
    lv[it] = labs[i];
    if (typ) { mv[it] = nmask[i]; sv[it] = nscore[i]; }
  }
  unsigned long long msks[8];
  int cntw = 0;
#pragma unroll
  for (int it = 0; it < 8; ++it) {
    bool m = (lv[it] == c) && (!typ || mv[it] > 0.5f);
    msks[it] = __ballot(m);
    cntw += __popcll(msks[it]);
  }
  if (lane == 0) ls_cntw[wv] = cntw;
  __syncthreads();
  int base = 0;
  for (int w2 = 0; w2 < wv; ++w2) base += ls_cntw[w2];
  // pass 2: write compacted list (+weights)
#pragma unroll
  for (int it = 0; it < 8; ++it) {
    bool m = (msks[it] >> lane) & 1ull;
    int pos = __popcll(msks[it] & ((1ull << lane) - 1ull));
    if (m) {
      ls_idx[base + pos] = rb + it * 64 + lane;
      ls_wt[base + pos] = typ ? sv[it] : 1.f;
    }
    base += __popcll(msks[it]);
  }
  __syncthreads();
  int count = ls_cntw[0] + ls_cntw[1] + ls_cntw[2] + ls_cntw[3];

  if (chunk == 0) {
    if (tid == 0) (typ ? (int*)(ws + OFF_CNT_T) : (int*)(ws + OFF_CNT_S))[c] = count;
    if (typ) {
      float s = 0.f;
      for (int i = tid; i < count; i += 256) s += ls_wt[i];
      s = brs256(s, sh4);
      if (tid == 0) ((float*)(ws + OFF_SW))[c] = s;
    }
  }

  // pack rows m = chunk + 8*wv + 32*k ; coalesced read, bf16 write, norms, moments
  unsigned short* pk = (unsigned short*)(ws + (typ ? OFF_PKT : OFF_PKS)) + (size_t)c * NN * DD;
  float* qarr = (float*)(ws + (typ ? OFF_QBFT : OFF_QBFS)) + c * NN;
  float* wtp  = (float*)(ws + OFF_WTP) + c * NN;
  float vax = 0.f, vay = 0.f, vaz = 0.f, vaw = 0.f, sqa = 0.f;
  for (int m = chunk + 8 * wv; m < count; m += 32) {
    int idx = ls_idx[m];
    float4 v = *(const float4*)&feats[(size_t)idx * DD + lane * 4];
    vax += v.x; vay += v.y; vaz += v.z; vaw += v.w;
    float raw = wred64(v.x * v.x + v.y * v.y + v.z * v.z + v.w * v.w);
    sqa += raw;
    unsigned ux = __float_as_uint(v.x); ux = (ux + 0x7fffu + ((ux >> 16) & 1u)) & 0xffff0000u;
    unsigned uy = __float_as_uint(v.y); uy = (uy + 0x7fffu + ((uy >> 16) & 1u)) & 0xffff0000u;
    unsigned uz = __float_as_uint(v.z); uz = (uz + 0x7fffu + ((uz >> 16) & 1u)) & 0xffff0000u;
    unsigned uw = __float_as_uint(v.w); uw = (uw + 0x7fffu + ((uw >> 16) & 1u)) & 0xffff0000u;
    float rx = __uint_as_float(ux), ry = __uint_as_float(uy);
    float rz = __uint_as_float(uz), rw = __uint_as_float(uw);
    ushort4 b4;
    b4.x = (unsigned short)(ux >> 16); b4.y = (unsigned short)(uy >> 16);
    b4.z = (unsigned short)(uz >> 16); b4.w = (unsigned short)(uw >> 16);
    *(ushort4*)&pk[(size_t)m * DD + lane * 4] = b4;
    float rq = wred64(rx * rx + ry * ry + rz * rz + rw * rw);
    if (lane == 0) {
      qarr[m] = rq;
      if (typ) wtp[m] = ls_wt[m];
    }
  }
  ls_mom[wv][lane * 4 + 0] = vax; ls_mom[wv][lane * 4 + 1] = vay;
  ls_mom[wv][lane * 4 + 2] = vaz; ls_mom[wv][lane * 4 + 3] = vaw;
  if (lane == 0) ls_sq[wv] = sqa;
  __syncthreads();
  float s = ls_mom[0][tid] + ls_mom[1][tid] + ls_mom[2][tid] + ls_mom[3][tid];
  float* vp = (float*)(ws + (typ ? OFF_VTP : OFF_VSP)) + (c * 8 + chunk) * 256;
  vp[tid] = s;
  if (tid == 0)
    ((float*)(ws + (typ ? OFF_SQTP : OFF_SQSP)))[c * 8 + chunk] = ls_sq[0] + ls_sq[1] + ls_sq[2] + ls_sq[3];
}

// ---------------- K2: 8 blocks, one class each ----------------
__global__ __launch_bounds__(256) void ecda_scalars(
    const float* __restrict__ cw, char* __restrict__ ws) {
  __shared__ float sh4[4];
  int c = blockIdx.x, tid = threadIdx.x;
  const float* vsp = (const float*)(ws + OFF_VSP);
  const float* vtp = (const float*)(ws + OFF_VTP);
  float vsd = 0.f, vtd = 0.f;
#pragma unroll
  for (int ch = 0; ch < 8; ++ch) {
    vsd += vsp[(c * 8 + ch) * 256 + tid];
    vtd += vtp[(c * 8 + ch) * 256 + tid];
  }
  ((float*)(ws + OFF_VS))[c * 256 + tid] = vsd;
  ((float*)(ws + OFF_VT))[c * 256 + tid] = vtd;
  float dss = brs256(vsd * vsd, sh4);
  float dtt = brs256(vtd * vtd, sh4);
  float dst = brs256(vsd * vtd, sh4);
  if (tid == 0) {
    const float* sqsp = (const float*)(ws + OFF_SQSP);
    const float* sqtp = (const float*)(ws + OFF_SQTP);
    float sqs = 0.f, sqt = 0.f;
    for (int ch = 0; ch < 8; ++ch) { sqs += sqsp[c * 8 + ch]; sqt += sqtp[c * 8 + ch]; }
    int nsi = ((const int*)(ws + OFF_CNT_S))[c];
    int nti = ((const int*)(ws + OFF_CNT_T))[c];
    float ns = (float)nsi, nt = (float)nti, n = ns + nt;
    float sumL2 = 2.f * ns * sqs - 2.f * dss
                + 2.f * nt * sqt - 2.f * dtt
                + 2.f * (nt * sqs + ns * sqt - 2.f * dst);
    float bw0 = sumL2 / fmaxf(n * n - n, 1.f) * 0.25f;    // /half, half=4
    float* invbw = (float*)(ws + OFF_INVBW);
    float mul = 1.f;
    for (int k = 0; k < 5; ++k) { invbw[c * 5 + k] = 1.f / (bw0 * mul + 1e-8f); mul *= 2.f; }
    float meanw = 0.f;
    for (int c2 = 0; c2 < NC; ++c2) meanw += cw[c2];
    meanw *= (1.f / NC);
    float attn = expf(meanw - cw[c]);                     // LAMBDA = 1
    float coef = (nsi >= 2 && nti >= 2) ? attn : 0.f;
    float swc = ((const float*)(ws + OFF_SW))[c];
    ((float*)(ws + OFF_SCC))[c] = coef / (ns * ns + 1e-8f);
    ((float*)(ws + OFF_SNN))[c] = coef / (swc * swc + 1e-8f);
    ((float*)(ws + OFF_SCN))[c] = -2.f * coef / (ns * swc + 1e-8f);
    float mx = fmaxf(nt, 1.f);
    float compact = (sqt - 2.f * dtt / mx + nt * dtt / (mx * mx)) / mx;
    ((float*)(ws + OFF_COEF))[c] = coef;
    ((float*)(ws + OFF_CCOMP))[c] = coef * 0.1f * compact;
  }
}

// ---------------- K3: 1537 blocks (1536 tiles + finale) ----------------
__global__ __launch_bounds__(256) void ecda_pairs(
    char* __restrict__ ws, float* __restrict__ out) {
  __shared__ float shred[4];
  __shared__ float dcen[28];
  int tid = threadIdx.x, bx = blockIdx.x;
  int wv = tid >> 6, lane = tid & 63;
  const int* cnt_s = (const int*)(ws + OFF_CNT_S);
  const int* cnt_t = (const int*)(ws + OFF_CNT_T);
  const float* vt = (const float*)(ws + OFF_VT);

  if (bx == 1536) {                        // finale: repulsion + base terms
    for (int t = wv; t < 28; t += 4) {
      int a = 0, r = t;
      while (r >= 7 - a) { r -= 7 - a; ++a; }
      int b = a + 1 + r;
      float ima = 1.f / fmaxf((float)cnt_t[a], 1.f);
      float imb = 1.f / fmaxf((float)cnt_t[b], 1.f);
      float4 x = *(const float4*)&vt[a * DD + lane * 4];
      float4 y = *(const float4*)&vt[b * DD + lane * 4];
      float dx = x.x * ima - y.x * imb, dy = x.y * ima - y.y * imb;
      float dz = x.z * ima - y.z * imb, dw = x.w * ima - y.w * imb;
      float s = wred64(dx * dx + dy * dy + dz * dz + dw * dw);
      if (lane == 0) dcen[t] = sqrtf(fmaxf(s, 1e-12f));
    }
    __syncthreads();
    if (tid == 0) {
      int nvalid = 0;
      for (int c = 0; c < NC; ++c) nvalid += (cnt_t[c] > 0);
      float sumD = 0.f; int np = 0; int p = 0;
      for (int a = 0; a < NC; ++a)
        for (int b = a + 1; b < NC; ++b) {
          if (cnt_t[a] > 0 && cnt_t[b] > 0) { sumD += dcen[p]; ++np; }
          ++p;
        }
      float repl = (nvalid > 1) ? (-sumD / fmaxf((float)np, 1.f)) : 0.f;
      const float* coefA = (const float*)(ws + OFF_COEF);
      const float* ccomp = (const float*)(ws + OFF_CCOMP);
      float base = 0.f, csum = 0.f;
      for (int c = 0; c < NC; ++c) { base += ccomp[c]; csum += coefA[c]; }
      base += 0.01f * repl * csum;
      atomicAdd(out, base);
    }
    return;
  }

  // -------- tile block --------
  int type  = bx >> 9;
  int c     = (bx >> 6) & 7;
  int rtile = (bx >> 3) & 7;
  int ctile = bx & 7;
  if (type <= 1 && ctile < rtile) return;

  int nsc = cnt_s[c], ntc = cnt_t[c];
  int na = (type == 1) ? ntc : nsc;
  int nb = (type == 0) ? nsc : ntc;
  int rbase = rtile * 32, cbase = ctile * 32;
  if (rbase >= na || cbase >= nb) return;
  const float* scarr = (type == 0) ? (const float*)(ws + OFF_SCC)
                     : (type == 1) ? (const float*)(ws + OFF_SNN)
                                   : (const float*)(ws + OFF_SCN);
  float scale = scarr[c];
  if (scale == 0.f) return;                // gated classes (coef==0)
  float factor = (type <= 1 && ctile > rtile) ? 2.f : 1.f;

  const unsigned short* pkS = (const unsigned short*)(ws + OFF_PKS) + (size_t)c * NN * DD;
  const unsigned short* pkT = (const unsigned short*)(ws + OFF_PKT) + (size_t)c * NN * DD;
  const float* qbS = (const float*)(ws + OFF_QBFS) + c * NN;
  const float* qbT = (const float*)(ws + OFF_QBFT) + c * NN;
  const float* wtp = (const float*)(ws + OFF_WTP) + c * NN;
  const unsigned short* pkA = (type == 1) ? pkT : pkS;
  const unsigned short* pkB = (type == 0) ? pkS : pkT;
  const float* qaB = (type == 1) ? qbT : qbS;
  const float* qbB = (type == 0) ? qbS : qbT;

  const float* invbw = (const float*)(ws + OFF_INVBW);
  float ib0 = invbw[c * 5 + 0], ib1 = invbw[c * 5 + 1], ib2 = invbw[c * 5 + 2];
  float ib3 = invbw[c * 5 + 3], ib4 = invbw[c * 5 + 4];

  int sr = (wv >> 1) * 16, sc2 = (wv & 1) * 16;
  int posA = rbase + sr + (lane & 15);
  int posB = cbase + sc2 + (lane & 15);
  int pAc = posA < na ? posA : (na - 1);
  int pBc = posB < nb ? posB : (nb - 1);
  const unsigned short* rowA = pkA + (size_t)pAc * DD + (lane >> 4) * 8;
  const unsigned short* rowB = pkB + (size_t)pBc * DD + (lane >> 4) * 8;

  f32x4 acc = {0.f, 0.f, 0.f, 0.f};
#pragma unroll
  for (int ks = 0; ks < 8; ++ks) {
    bf16x8 af = *(const bf16x8*)(rowA + ks * 32);
    bf16x8 bf = *(const bf16x8*)(rowB + ks * 32);
    acc = __builtin_amdgcn_mfma_f32_16x16x32_bf16(af, bf, acc, 0, 0, 0);
  }

  // epilogue: lane holds D[row][col], col = cbase+sc2+(lane&15), row = rowbase+r
  bool jval = (posB < nb);
  float knj = qbB[pBc];
  float wj = (type == 0) ? 1.f : wtp[pBc];
  int rowbase = rbase + sr + ((lane >> 4) << 2);
  float partial = 0.f;
#pragma unroll
  for (int r = 0; r < 4; ++r) {
    int ip = rowbase + r;
    bool val = jval && (ip < na);
    int ipc = ip < na ? ip : (na - 1);
    float qA = qaB[ipc];
    float wA = (type == 1) ? wtp[ipc] : 1.f;
    float d2 = fmaxf(qA + knj - 2.f * acc[r], 0.f);
    float e = __expf(-d2 * ib0) + __expf(-d2 * ib1) + __expf(-d2 * ib2)
            + __expf(-d2 * ib3) + __expf(-d2 * ib4);
    partial += val ? wA * wj * e : 0.f;
  }
  partial = wred64(partial);
  if (lane == 0) shred[wv] = partial;
  __syncthreads();
  if (tid == 0) {
    float tot = shred[0] + shred[1] + shred[2] + shred[3];
    atomicAdd(out, scale * factor * tot);
  }
}

extern "C" void kernel_launch(void* const* d_in, const int* in_sizes, int n_in,
                              void* d_out, int out_size, void* d_ws, size_t ws_size,
                              hipStream_t stream) {
  const float* cfeat  = (const float*)d_in[0];
  const float* nfeat  = (const float*)d_in[1];
  const int*   clab   = (const int*)d_in[2];
  const int*   nlab   = (const int*)d_in[3];
  const float* nmask  = (const float*)d_in[4];
  const float* nscore = (const float*)d_in[5];
  const float* cw     = (const float*)d_in[6];
  float* out = (float*)d_out;
  char* ws = (char*)d_ws;

  ecda_pack<<<128, 256, 0, stream>>>(cfeat, nfeat, clab, nlab, nmask, nscore,
                                     ws, out);
  ecda_scalars<<<8, 256, 0, stream>>>(cw, ws);
  ecda_pairs<<<1537, 256, 0, stream>>>(ws, out);
}

// Round 7
// 34.075 us; speedup vs baseline: 3.8912x; 1.0501x over previous
//
#include <hip/hip_runtime.h>
#include <math.h>

// ECDA loss, 3-kernel packed formulation, latency-tuned.
// K1 ecda_pack: 256 blocks; ballot-scan labels, pack class rows into
//   compacted bf16 matrices + norms + weights + partial moments (4-row batch).
// K2 ecda_scalars: per-class reduction -> scalars + 32B per-(type,class) header.
// K3 ecda_pairs: pure MFMA pair tiles (header prologue) + finale block.

static constexpr int NC = 8;
static constexpr int NN = 2048;
static constexpr int DD = 256;

// workspace byte offsets
static constexpr int OFF_CNT_S = 0;         // 8 int
static constexpr int OFF_CNT_T = 64;        // 8 int
static constexpr int OFF_SW    = 128;       // 8 f32
static constexpr int OFF_COEF  = 192;       // 8 f32 (attn coef, gated)
static constexpr int OFF_CCOMP = 256;       // 8 f32 (coef*0.1*compact)
static constexpr int OFF_SQSP  = 1024;      // 8*16 f32 partial raw-norm sums (clean)
static constexpr int OFF_SQTP  = 1536;      // 8*16 f32 (noisy)
static constexpr int OFF_HDR   = 2048;      // 24*8 f32 headers [type*8+c]: na,nb,scale,ib0..ib4
static constexpr int OFF_VSP   = 4096;      // 8c*16ch*256 f32 partial moments (clean)
static constexpr int OFF_VTP   = 135168;    // same (noisy)
static constexpr int OFF_VS    = 266240;    // 8*256 f32 reduced
static constexpr int OFF_VT    = 274432;    // 8*256 f32
static constexpr int OFF_QBFS  = 282624;    // 8*2048 f32 bf16-norms by position (clean)
static constexpr int OFF_QBFT  = 348160;    // 8*2048 f32 (noisy)
static constexpr int OFF_WTP   = 413696;    // 8*2048 f32 weights by position
static constexpr size_t OFF_PKS = 479232;   // 8*2048*256 bf16 packed clean (8 MB)
static constexpr size_t OFF_PKT = 8867840;  // packed noisy (8 MB)
// total ~17.3 MB

typedef __attribute__((ext_vector_type(8))) short bf16x8;
typedef __attribute__((ext_vector_type(4))) float f32x4;

__device__ inline float wred64(float v) {
  for (int o = 32; o > 0; o >>= 1) v += __shfl_xor(v, o, 64);
  return v;
}
__device__ inline float brs256(float v, float* sh4) {
  for (int o = 32; o > 0; o >>= 1) v += __shfl_xor(v, o, 64);
  int w = threadIdx.x >> 6, ln = threadIdx.x & 63;
  __syncthreads();
  if (ln == 0) sh4[w] = v;
  __syncthreads();
  float r = 0.f;
  if (threadIdx.x == 0) r = sh4[0] + sh4[1] + sh4[2] + sh4[3];
  return r;
}

// ---------------- K1: 256 blocks = typ(2) x class(8) x chunk(16) ----------------
__global__ __launch_bounds__(256) void ecda_pack(
    const float* __restrict__ cfeat, const float* __restrict__ nfeat,
    const int* __restrict__ clab, const int* __restrict__ nlab,
    const float* __restrict__ nmask, const float* __restrict__ nscore,
    char* __restrict__ ws, float* __restrict__ out) {
  __shared__ int   ls_idx[NN];
  __shared__ float ls_wt[NN];
  __shared__ int   ls_cntw[4];
  __shared__ float ls_mom[4][256];
  __shared__ float ls_sq[4];
  __shared__ float sh4[4];
  int tid = threadIdx.x, bx = blockIdx.x;
  int wv = tid >> 6, lane = tid & 63;
  int typ = bx >> 7, c = (bx >> 4) & 7, chunk = bx & 15;

  if (bx == 0 && tid == 0) out[0] = 0.f;

  const int* labs = typ ? nlab : clab;
  const float* feats = typ ? nfeat : cfeat;

  // pass 1: per-wave match masks over its 512 rows
  int rb = wv * 512;
  int lv[8]; float mv[8], sv[8];
#pragma unroll
  for (int it = 0; it < 8; ++it) {
    int i = rb + it * 64 + lane;
    lv[it] = labs[i];
    if (typ) { mv[it] = nmask[i]; sv[it] = nscore[i]; }
  }
  unsigned long long msks[8];
  int cntw = 0;
#pragma unroll
  for (int it = 0; it < 8; ++it) {
    bool m = (lv[it] == c) && (!typ || mv[it] > 0.5f);
    msks[it] = __ballot(m);
    cntw += __popcll(msks[it]);
  }
  if (lane == 0) ls_cntw[wv] = cntw;
  __syncthreads();
  int base = 0;
  for (int w2 = 0; w2 < wv; ++w2) base += ls_cntw[w2];
  // pass 2: write compacted list (+weights)
#pragma unroll
  for (int it = 0; it < 8; ++it) {
    bool m = (msks[it] >> lane) & 1ull;
    int pos = __popcll(msks[it] & ((1ull << lane) - 1ull));
    if (m) {
      ls_idx[base + pos] = rb + it * 64 + lane;
      ls_wt[base + pos] = typ ? sv[it] : 1.f;
    }
    base += __popcll(msks[it]);
  }
  __syncthreads();
  int count = ls_cntw[0] + ls_cntw[1] + ls_cntw[2] + ls_cntw[3];

  if (chunk == 0) {
    if (tid == 0) (typ ? (int*)(ws + OFF_CNT_T) : (int*)(ws + OFF_CNT_S))[c] = count;
    if (typ) {
      float s = 0.f;
      for (int i = tid; i < count; i += 256) s += ls_wt[i];
      s = brs256(s, sh4);
      if (tid == 0) ((float*)(ws + OFF_SW))[c] = s;
    }
  }

  // pack rows; per-wave m-stream = chunk*4 + wv (stride 64), 4-row batches
  unsigned short* pk = (unsigned short*)(ws + (typ ? OFF_PKT : OFF_PKS)) + (size_t)c * NN * DD;
  float* qarr = (float*)(ws + (typ ? OFF_QBFT : OFF_QBFS)) + c * NN;
  float* wtp  = (float*)(ws + OFF_WTP) + c * NN;
  float vax = 0.f, vay = 0.f, vaz = 0.f, vaw = 0.f, sqa = 0.f;
  int mstart = chunk * 4 + wv;
  for (int m0 = mstart; m0 < count; m0 += 256) {
    int mm[4]; bool act[4]; float4 v[4];
#pragma unroll
    for (int b = 0; b < 4; ++b) {
      int m = m0 + b * 64;
      act[b] = (m < count);
      mm[b] = act[b] ? m : m0;
    }
#pragma unroll
    for (int b = 0; b < 4; ++b) {
      int idx = ls_idx[mm[b]];
      v[b] = *(const float4*)&feats[(size_t)idx * DD + lane * 4];
    }
#pragma unroll
    for (int b = 0; b < 4; ++b) {
      float raw = wred64(v[b].x * v[b].x + v[b].y * v[b].y
                       + v[b].z * v[b].z + v[b].w * v[b].w);
      unsigned ux = __float_as_uint(v[b].x); ux = (ux + 0x7fffu + ((ux >> 16) & 1u)) & 0xffff0000u;
      unsigned uy = __float_as_uint(v[b].y); uy = (uy + 0x7fffu + ((uy >> 16) & 1u)) & 0xffff0000u;
      unsigned uz = __float_as_uint(v[b].z); uz = (uz + 0x7fffu + ((uz >> 16) & 1u)) & 0xffff0000u;
      unsigned uw = __float_as_uint(v[b].w); uw = (uw + 0x7fffu + ((uw >> 16) & 1u)) & 0xffff0000u;
      float rx = __uint_as_float(ux), ry = __uint_as_float(uy);
      float rz = __uint_as_float(uz), rw = __uint_as_float(uw);
      float rq = wred64(rx * rx + ry * ry + rz * rz + rw * rw);
      if (act[b]) {
        vax += v[b].x; vay += v[b].y; vaz += v[b].z; vaw += v[b].w;
        sqa += raw;
        ushort4 b4;
        b4.x = (unsigned short)(ux >> 16); b4.y = (unsigned short)(uy >> 16);
        b4.z = (unsigned short)(uz >> 16); b4.w = (unsigned short)(uw >> 16);
        *(ushort4*)&pk[(size_t)mm[b] * DD + lane * 4] = b4;
        if (lane == 0) {
          qarr[mm[b]] = rq;
          if (typ) wtp[mm[b]] = ls_wt[mm[b]];
        }
      }
    }
  }
  ls_mom[wv][lane * 4 + 0] = vax; ls_mom[wv][lane * 4 + 1] = vay;
  ls_mom[wv][lane * 4 + 2] = vaz; ls_mom[wv][lane * 4 + 3] = vaw;
  if (lane == 0) ls_sq[wv] = sqa;
  __syncthreads();
  float s = ls_mom[0][tid] + ls_mom[1][tid] + ls_mom[2][tid] + ls_mom[3][tid];
  float* vp = (float*)(ws + (typ ? OFF_VTP : OFF_VSP)) + (c * 16 + chunk) * 256;
  vp[tid] = s;
  if (tid == 0)
    ((float*)(ws + (typ ? OFF_SQTP : OFF_SQSP)))[c * 16 + chunk] =
        ls_sq[0] + ls_sq[1] + ls_sq[2] + ls_sq[3];
}

// ---------------- K2: 8 blocks, one class each ----------------
__global__ __launch_bounds__(256) void ecda_scalars(
    const float* __restrict__ cw, char* __restrict__ ws) {
  __shared__ float sh4[4];
  int c = blockIdx.x, tid = threadIdx.x;
  const float* vsp = (const float*)(ws + OFF_VSP);
  const float* vtp = (const float*)(ws + OFF_VTP);
  float vsd = 0.f, vtd = 0.f;
#pragma unroll
  for (int ch = 0; ch < 16; ++ch) {
    vsd += vsp[(c * 16 + ch) * 256 + tid];
    vtd += vtp[(c * 16 + ch) * 256 + tid];
  }
  ((float*)(ws + OFF_VS))[c * 256 + tid] = vsd;
  ((float*)(ws + OFF_VT))[c * 256 + tid] = vtd;
  float dss = brs256(vsd * vsd, sh4);
  float dtt = brs256(vtd * vtd, sh4);
  float dst = brs256(vsd * vtd, sh4);
  if (tid == 0) {
    const float* sqsp = (const float*)(ws + OFF_SQSP);
    const float* sqtp = (const float*)(ws + OFF_SQTP);
    float sqs = 0.f, sqt = 0.f;
    for (int ch = 0; ch < 16; ++ch) { sqs += sqsp[c * 16 + ch]; sqt += sqtp[c * 16 + ch]; }
    int nsi = ((const int*)(ws + OFF_CNT_S))[c];
    int nti = ((const int*)(ws + OFF_CNT_T))[c];
    float ns = (float)nsi, nt = (float)nti, n = ns + nt;
    float sumL2 = 2.f * ns * sqs - 2.f * dss
                + 2.f * nt * sqt - 2.f * dtt
                + 2.f * (nt * sqs + ns * sqt - 2.f * dst);
    float bw0 = sumL2 / fmaxf(n * n - n, 1.f) * 0.25f;    // /half, half=4
    float ib[5];
    float mul = 1.f;
    for (int k = 0; k < 5; ++k) { ib[k] = 1.f / (bw0 * mul + 1e-8f); mul *= 2.f; }
    float meanw = 0.f;
    for (int c2 = 0; c2 < NC; ++c2) meanw += cw[c2];
    meanw *= (1.f / NC);
    float attn = expf(meanw - cw[c]);                     // LAMBDA = 1
    float coef = (nsi >= 2 && nti >= 2) ? attn : 0.f;
    float swc = ((const float*)(ws + OFF_SW))[c];
    float scc = coef / (ns * ns + 1e-8f);
    float snn = coef / (swc * swc + 1e-8f);
    float scn = -2.f * coef / (ns * swc + 1e-8f);
    // headers: [type*8+c]*8 floats = {na, nb, scale, ib0, ib1, ib2, ib3, ib4}
    float* hdr = (float*)(ws + OFF_HDR);
    for (int ty = 0; ty < 3; ++ty) {
      float* h = hdr + (ty * 8 + c) * 8;
      int na = (ty == 1) ? nti : nsi;
      int nb = (ty == 0) ? nsi : nti;
      h[0] = __int_as_float(na);
      h[1] = __int_as_float(nb);
      h[2] = (ty == 0) ? scc : (ty == 1) ? snn : scn;
      h[3] = ib[0]; h[4] = ib[1]; h[5] = ib[2]; h[6] = ib[3]; h[7] = ib[4];
    }
    float mx = fmaxf(nt, 1.f);
    float compact = (sqt - 2.f * dtt / mx + nt * dtt / (mx * mx)) / mx;
    ((float*)(ws + OFF_COEF))[c] = coef;
    ((float*)(ws + OFF_CCOMP))[c] = coef * 0.1f * compact;
  }
}

// ---------------- K3: 1537 blocks (1536 tiles + finale) ----------------
__global__ __launch_bounds__(256) void ecda_pairs(
    char* __restrict__ ws, float* __restrict__ out) {
  __shared__ float shred[4];
  __shared__ float dcen[28];
  int tid = threadIdx.x, bx = blockIdx.x;
  int wv = tid >> 6, lane = tid & 63;

  if (bx == 1536) {                        // finale: repulsion + base terms
    const int* cnt_t = (const int*)(ws + OFF_CNT_T);
    const float* vt = (const float*)(ws + OFF_VT);
    for (int t = wv; t < 28; t += 4) {
      int a = 0, r = t;
      while (r >= 7 - a) { r -= 7 - a; ++a; }
      int b = a + 1 + r;
      float ima = 1.f / fmaxf((float)cnt_t[a], 1.f);
      float imb = 1.f / fmaxf((float)cnt_t[b], 1.f);
      float4 x = *(const float4*)&vt[a * DD + lane * 4];
      float4 y = *(const float4*)&vt[b * DD + lane * 4];
      float dx = x.x * ima - y.x * imb, dy = x.y * ima - y.y * imb;
      float dz = x.z * ima - y.z * imb, dw = x.w * ima - y.w * imb;
      float s = wred64(dx * dx + dy * dy + dz * dz + dw * dw);
      if (lane == 0) dcen[t] = sqrtf(fmaxf(s, 1e-12f));
    }
    __syncthreads();
    if (tid == 0) {
      int nvalid = 0;
      for (int c = 0; c < NC; ++c) nvalid += (cnt_t[c] > 0);
      float sumD = 0.f; int np = 0; int p = 0;
      for (int a = 0; a < NC; ++a)
        for (int b = a + 1; b < NC; ++b) {
          if (cnt_t[a] > 0 && cnt_t[b] > 0) { sumD += dcen[p]; ++np; }
          ++p;
        }
      float repl = (nvalid > 1) ? (-sumD / fmaxf((float)np, 1.f)) : 0.f;
      const float* coefA = (const float*)(ws + OFF_COEF);
      const float* ccomp = (const float*)(ws + OFF_CCOMP);
      float base = 0.f, csum = 0.f;
      for (int c = 0; c < NC; ++c) { base += ccomp[c]; csum += coefA[c]; }
      base += 0.01f * repl * csum;
      atomicAdd(out, base);
    }
    return;
  }

  // -------- tile block --------
  int type  = bx >> 9;
  int c     = (bx >> 6) & 7;
  int rtile = (bx >> 3) & 7;
  int ctile = bx & 7;
  if (type <= 1 && ctile < rtile) return;  // symmetric: upper only (no loads)

  const f32x4* H = (const f32x4*)((const char*)ws + OFF_HDR) + (type * 8 + c) * 2;
  f32x4 h0 = H[0];
  int na = __float_as_int(h0[0]);
  int nb = __float_as_int(h0[1]);
  float scale = h0[2];
  int rbase = rtile * 32, cbase = ctile * 32;
  if (scale == 0.f || rbase >= na || cbase >= nb) return;
  f32x4 h1 = H[1];
  float ib0 = h0[3], ib1 = h1[0], ib2 = h1[1], ib3 = h1[2], ib4 = h1[3];
  float factor = (type <= 1 && ctile > rtile) ? 2.f : 1.f;

  const unsigned short* pkS = (const unsigned short*)(ws + OFF_PKS) + (size_t)c * NN * DD;
  const unsigned short* pkT = (const unsigned short*)(ws + OFF_PKT) + (size_t)c * NN * DD;
  const float* qbS = (const float*)(ws + OFF_QBFS) + c * NN;
  const float* qbT = (const float*)(ws + OFF_QBFT) + c * NN;
  const float* wtp = (const float*)(ws + OFF_WTP) + c * NN;
  const unsigned short* pkA = (type == 1) ? pkT : pkS;
  const unsigned short* pkB = (type == 0) ? pkS : pkT;
  const float* qaB = (type == 1) ? qbT : qbS;
  const float* qbB = (type == 0) ? qbS : qbT;

  int sr = (wv >> 1) * 16, sc2 = (wv & 1) * 16;
  int posA = rbase + sr + (lane & 15);
  int posB = cbase + sc2 + (lane & 15);
  int pAc = posA < na ? posA : (na - 1);
  int pBc = posB < nb ? posB : (nb - 1);
  const unsigned short* rowA = pkA + (size_t)pAc * DD + (lane >> 4) * 8;
  const unsigned short* rowB = pkB + (size_t)pBc * DD + (lane >> 4) * 8;

  f32x4 acc = {0.f, 0.f, 0.f, 0.f};
#pragma unroll
  for (int ks = 0; ks < 8; ++ks) {
    bf16x8 af = *(const bf16x8*)(rowA + ks * 32);
    bf16x8 bf = *(const bf16x8*)(rowB + ks * 32);
    acc = __builtin_amdgcn_mfma_f32_16x16x32_bf16(af, bf, acc, 0, 0, 0);
  }

  // epilogue: lane holds D[row][col], col = cbase+sc2+(lane&15), row = rowbase+r
  bool jval = (posB < nb);
  float knj = qbB[pBc];
  float wj = (type == 0) ? 1.f : wtp[pBc];
  int rowbase = rbase + sr + ((lane >> 4) << 2);          // multiple of 4
  f32x4 qA4 = *(const f32x4*)&qaB[rowbase];               // poison past count is gated
  f32x4 wA4 = {1.f, 1.f, 1.f, 1.f};
  if (type == 1) wA4 = *(const f32x4*)&wtp[rowbase];
  float partial = 0.f;
#pragma unroll
  for (int r = 0; r < 4; ++r) {
    int ip = rowbase + r;
    bool val = jval && (ip < na);
    float d2 = fmaxf(qA4[r] + knj - 2.f * acc[r], 0.f);
    float e = __expf(-d2 * ib0) + __expf(-d2 * ib1) + __expf(-d2 * ib2)
            + __expf(-d2 * ib3) + __expf(-d2 * ib4);
    float wgt = (type == 1) ? wA4[r] * wj : wj;
    partial += val ? wgt * e : 0.f;
  }
  partial = wred64(partial);
  if (lane == 0) shred[wv] = partial;
  __syncthreads();
  if (tid == 0) {
    float tot = shred[0] + shred[1] + shred[2] + shred[3];
    atomicAdd(out, scale * factor * tot);
  }
}

extern "C" void kernel_launch(void* const* d_in, const int* in_sizes, int n_in,
                              void* d_out, int out_size, void* d_ws, size_t ws_size,
                              hipStream_t stream) {
  const float* cfeat  = (const float*)d_in[0];
  const float* nfeat  = (const float*)d_in[1];
  const int*   clab   = (const int*)d_in[2];
  const int*   nlab   = (const int*)d_in[3];
  const float* nmask  = (const float*)d_in[4];
  const float* nscore = (const float*)d_in[5];
  const float* cw     = (const float*)d_in[6];
  float* out = (float*)d_out;
  char* ws = (char*)d_ws;

  ecda_pack<<<256, 256, 0, stream>>>(cfeat, nfeat, clab, nlab, nmask, nscore,
                                     ws, out);
  ecda_scalars<<<8, 256, 0, stream>>>(cw, ws);
  ecda_pairs<<<1537, 256, 0, stream>>>(ws, out);
}